// Round 1
// baseline (423.907 us; speedup 1.0000x reference)
//
#include <hip/hip_runtime.h>

#define LIF_THRESH 0.5f
#define LIF_TAU    0.25f
#define LIF_T      16

// x layout: [B, T, C, H, W] fp32. One thread owns 4 consecutive spatial
// elements (float4) of one batch b, loops the T=16 recurrence in registers.
// Per-t addresses across the wave are contiguous -> fully coalesced 16B/lane.
__global__ __launch_bounds__(256) void lif_fwd_kernel(
    const float4* __restrict__ x, float4* __restrict__ out,
    int vec_per_t,   // (C*H*W)/4 elements per timestep slab, in float4 units
    int total_vec)   // B * vec_per_t
{
    int tid = blockIdx.x * blockDim.x + threadIdx.x;
    if (tid >= total_vec) return;

    int b     = tid / vec_per_t;          // vec_per_t is 32768 (pow2) -> shift
    int inner = tid - b * vec_per_t;

    size_t base = (size_t)b * LIF_T * vec_per_t + inner;
    const float4* xp = x   + base;
    float4*       op = out + base;

    float mx = 0.f, my = 0.f, mz = 0.f, mw = 0.f;

#pragma unroll
    for (int t = 0; t < LIF_T; ++t) {
        float4 xt = xp[(size_t)t * vec_per_t];
        float4 s;

        mx = mx * LIF_TAU + xt.x;
        bool fx = (mx >= LIF_THRESH); s.x = fx ? 1.f : 0.f; mx = fx ? 0.f : mx;

        my = my * LIF_TAU + xt.y;
        bool fy = (my >= LIF_THRESH); s.y = fy ? 1.f : 0.f; my = fy ? 0.f : my;

        mz = mz * LIF_TAU + xt.z;
        bool fz = (mz >= LIF_THRESH); s.z = fz ? 1.f : 0.f; mz = fz ? 0.f : mz;

        mw = mw * LIF_TAU + xt.w;
        bool fw = (mw >= LIF_THRESH); s.w = fw ? 1.f : 0.f; mw = fw ? 0.f : mw;

        op[(size_t)t * vec_per_t] = s;
    }
}

extern "C" void kernel_launch(void* const* d_in, const int* in_sizes, int n_in,
                              void* d_out, int out_size, void* d_ws, size_t ws_size,
                              hipStream_t stream) {
    const float* x = (const float*)d_in[0];
    float* out = (float*)d_out;

    const int n = in_sizes[0];            // B*T*C*H*W = 67,108,864
    const int chw = 128 * 32 * 32;        // 131072 (C*H*W from reference)
    const int vec_per_t = chw / 4;        // 32768
    const int total_vec = (n / LIF_T) / 4; // B * vec_per_t = 1,048,576

    const int block = 256;
    const int grid = (total_vec + block - 1) / block;  // 4096

    lif_fwd_kernel<<<grid, block, 0, stream>>>(
        (const float4*)x, (float4*)out, vec_per_t, total_vec);
}

// Round 3
// 413.749 us; speedup vs baseline: 1.0246x; 1.0246x over previous
//
#include <hip/hip_runtime.h>

// LIF forward scan: x [B=32, T=16, C=128, H=32, W=32] fp32 -> spikes, same shape.
// Strictly memory-bound: 256 MiB in + 256 MiB out, ~85 us floor at 6.3 TB/s.
// One thread owns 4 consecutive spatial elements (one float4) of one batch and
// runs the T=16 recurrence in registers. All 16 t-loads are batched up-front
// into xt[16] for maximal memory-level parallelism; nontemporal hints keep the
// streaming traffic from thrashing L2.

#define LIF_THRESH 0.5f
#define LIF_TAU    0.25f

typedef float f4 __attribute__((ext_vector_type(4)));  // native vec: nt builtins OK

constexpr int T         = 16;
constexpr int CHW       = 128 * 32 * 32;   // 131072
constexpr int VEC_PER_T = CHW / 4;         // 32768 float4 per t-slab (pow2)
constexpr int B         = 32;
constexpr int TOTAL_VEC = B * VEC_PER_T;   // 1,048,576 threads

__global__ __launch_bounds__(256) void lif_fwd_kernel(
    const f4* __restrict__ x, f4* __restrict__ out)
{
    int tid = blockIdx.x * 256 + threadIdx.x;   // grid sized exactly

    int b     = tid >> 15;                 // / VEC_PER_T
    int inner = tid & (VEC_PER_T - 1);

    size_t base = (size_t)b * (T * VEC_PER_T) + inner;
    const f4* xp = x   + base;
    f4*       op = out + base;

    // Phase 1: issue all 16 independent loads back-to-back (64 KiB/wave in flight).
    f4 xt[T];
#pragma unroll
    for (int t = 0; t < T; ++t)
        xt[t] = __builtin_nontemporal_load(&xp[t * VEC_PER_T]);

    // Phase 2: serial recurrence in registers; store each step (nontemporal).
    float mx = 0.f, my = 0.f, mz = 0.f, mw = 0.f;
#pragma unroll
    for (int t = 0; t < T; ++t) {
        f4 s;

        mx = mx * LIF_TAU + xt[t].x;
        bool fx = (mx >= LIF_THRESH); s.x = fx ? 1.f : 0.f; mx = fx ? 0.f : mx;

        my = my * LIF_TAU + xt[t].y;
        bool fy = (my >= LIF_THRESH); s.y = fy ? 1.f : 0.f; my = fy ? 0.f : my;

        mz = mz * LIF_TAU + xt[t].z;
        bool fz = (mz >= LIF_THRESH); s.z = fz ? 1.f : 0.f; mz = fz ? 0.f : mz;

        mw = mw * LIF_TAU + xt[t].w;
        bool fw = (mw >= LIF_THRESH); s.w = fw ? 1.f : 0.f; mw = fw ? 0.f : mw;

        __builtin_nontemporal_store(s, &op[t * VEC_PER_T]);
    }
}

extern "C" void kernel_launch(void* const* d_in, const int* in_sizes, int n_in,
                              void* d_out, int out_size, void* d_ws, size_t ws_size,
                              hipStream_t stream) {
    const f4* x = (const f4*)d_in[0];
    f4* out = (f4*)d_out;

    const int block = 256;
    const int grid  = TOTAL_VEC / block;   // 4096

    lif_fwd_kernel<<<grid, block, 0, stream>>>(x, out);
}